// Round 1
// 1184.515 us; speedup vs baseline: 1.4091x; 1.4091x over previous
//
#include <hip/hip_runtime.h>
#include <hip/hip_bf16.h>
#include <math.h>
#include <stdint.h>

// CodeGenAttention: B=2, S=2048, H=4096, NH=16, D=256, ROT=64, MP=4
// detect dtype -> convert/transpose to bf16 -> QKV GEMM (256x256 8-wave,
// 4-phase counted-vmcnt pipeline, XOR-swizzled LDS, setprio, XCD swizzle;
// V stored transposed [b,h,d,s]) -> rope -> flash attn -> out GEMM.

typedef __attribute__((ext_vector_type(8))) short bf16x8;
typedef __attribute__((ext_vector_type(4))) float f32x4;
typedef unsigned short u16;

__device__ __forceinline__ u16 f2b(float f) {
    __hip_bfloat16 h = __float2bfloat16(f);
    return *reinterpret_cast<u16*>(&h);
}
__device__ __forceinline__ float b2f(u16 u) {
    __hip_bfloat16 h = *reinterpret_cast<__hip_bfloat16*>(&u);
    return __bfloat162float(h);
}

__device__ __forceinline__ void load_lds16(const u16* g, u16* l) {
    __builtin_amdgcn_global_load_lds((const __attribute__((address_space(1))) void*)g,
                                     (__attribute__((address_space(3))) void*)l, 16, 0, 0);
}

// ---------------- dtype probe ---------------------------------------------
__global__ void detect_kernel(const u16* __restrict__ h, int* __restrict__ flag)
{
    int lane = threadIdx.x & 63;
    int cnt = 0;
    for (int i = lane; i < 8192; i += 64) {
        int e = (h[i] >> 7) & 0xFF;
        cnt += (e >= 0xC0);
    }
    for (int off = 32; off > 0; off >>= 1) cnt += __shfl_down(cnt, off, 64);
    if (lane == 0) *flag = (cnt > 0) ? 1 : 0;
}

// ---------------- elementwise convert to bf16 (8 elems/thread) ------------
__global__ __launch_bounds__(256)
void convert_kernel(const void* __restrict__ in, const int* __restrict__ flag,
                    u16* __restrict__ outp, int n8)
{
    int idx = blockIdx.x * 256 + threadIdx.x;
    if (idx >= n8) return;
    if (*flag) {
        const float* x = (const float*)in;
        f32x4 a = *reinterpret_cast<const f32x4*>(&x[(size_t)idx * 8]);
        f32x4 b = *reinterpret_cast<const f32x4*>(&x[(size_t)idx * 8 + 4]);
        u16 t[8];
#pragma unroll
        for (int j = 0; j < 4; j++) { t[j] = f2b(a[j]); t[4 + j] = f2b(b[j]); }
        *reinterpret_cast<uint4*>(&outp[(size_t)idx * 8]) = *reinterpret_cast<uint4*>(t);
    } else {
        ((uint4*)outp)[idx] = ((const uint4*)in)[idx];
    }
}

// ---------------- transpose + convert: W[K,N] -> Wt[N,K] bf16 -------------
__global__ __launch_bounds__(256)
void transpose_conv_kernel(const void* __restrict__ Wv, const int* __restrict__ flag,
                           int K, int N, u16* __restrict__ Wt)
{
    __shared__ u16 T[64][68];
    const int tid = threadIdx.x;
    const int k0 = blockIdx.y * 64, n0 = blockIdx.x * 64;
    const int kr = tid >> 4, nc = tid & 15;
    if (*flag) {
        const float* W = (const float*)Wv;
#pragma unroll
        for (int kk = 0; kk < 4; kk++) {
            int k = kr + kk * 16;
            f32x4 v = *reinterpret_cast<const f32x4*>(&W[(size_t)(k0 + k) * N + n0 + nc * 4]);
#pragma unroll
            for (int j = 0; j < 4; j++) T[nc * 4 + j][k] = f2b(v[j]);
        }
    } else {
        const u16* W = (const u16*)Wv;
#pragma unroll
        for (int kk = 0; kk < 4; kk++) {
            int k = kr + kk * 16;
            ushort4 v = *reinterpret_cast<const ushort4*>(&W[(size_t)(k0 + k) * N + n0 + nc * 4]);
            T[nc * 4 + 0][k] = v.x; T[nc * 4 + 1][k] = v.y;
            T[nc * 4 + 2][k] = v.z; T[nc * 4 + 3][k] = v.w;
        }
    }
    __syncthreads();
#pragma unroll
    for (int it = 0; it < 2; it++) {
        int ch = tid + it * 256;
        int n = ch >> 3, kc = ch & 7;
        const uint2* s2 = reinterpret_cast<const uint2*>(&T[n][kc * 8]);
        uint2 a = s2[0], b = s2[1];
        uint4 o; o.x = a.x; o.y = a.y; o.z = b.x; o.w = b.y;
        *reinterpret_cast<uint4*>(&Wt[(size_t)(n0 + n) * K + k0 + kc * 8]) = o;
    }
}

// ---------------- GEMM: C[M,N] = A[M,K] @ Bt[N,K]^T, all bf16 -------------
// 256x256 tile, BK=64, 512 threads = 8 waves (2M x 4N), per-wave C 128x64.
// LDS 128 KiB: As/Bs[2][256][64], chunk-XOR swizzle (p = c ^ (row&7)) applied
// via pre-swizzled global source (linear global_load_lds dest) + swizzled
// ds_read -> conflict-free ds_read_b128.
// 4 phases / K-tile: {ds_read quad frags | issue 1 half-tile for kt+1 |
// counted vmcnt | s_barrier | setprio(1) 16 MFMA setprio(0)}. Never vmcnt(0)
// in the main loop; last K-tile peeled with vmcnt(2)/vmcnt(0).
// mode 0: plain store. mode 1: qkv scatter, V transposed.

#define WAITV(N) asm volatile("s_waitcnt vmcnt(" #N ")" ::: "memory")
#define BARS()   do { asm volatile("s_barrier" ::: "memory"); \
                      __builtin_amdgcn_sched_barrier(0); } while (0)

#define RD_A(IOFF)                                                            \
    _Pragma("unroll")                                                         \
    for (int il = 0; il < 4; ++il) {                                          \
        aF[il][0] = *(const bf16x8*)(Ac + aR + (il + IOFF) * 2048 + p0);      \
        aF[il][1] = *(const bf16x8*)(Ac + aR + (il + IOFF) * 2048 + p1);      \
    }

#define RD_B(BF, JOFF)                                                        \
    _Pragma("unroll")                                                         \
    for (int j = 0; j < 2; ++j) {                                             \
        BF[j][0] = *(const bf16x8*)(Bc + bR + (j + JOFF) * 4096 + p0);        \
        BF[j][1] = *(const bf16x8*)(Bc + bR + (j + JOFF) * 4096 + p1);        \
    }

#define MFMA_BLK(IOFF, BF, JOFF)                                              \
    __builtin_amdgcn_s_setprio(1);                                            \
    _Pragma("unroll")                                                         \
    for (int il = 0; il < 4; ++il)                                            \
        _Pragma("unroll")                                                     \
        for (int j = 0; j < 2; ++j) {                                         \
            acc[il + IOFF][j + JOFF] = __builtin_amdgcn_mfma_f32_16x16x32_bf16( \
                aF[il][0], BF[j][0], acc[il + IOFF][j + JOFF], 0, 0, 0);      \
            acc[il + IOFF][j + JOFF] = __builtin_amdgcn_mfma_f32_16x16x32_bf16( \
                aF[il][1], BF[j][1], acc[il + IOFF][j + JOFF], 0, 0, 0);      \
        }                                                                     \
    __builtin_amdgcn_s_setprio(0);

__global__ __launch_bounds__(512, 2)
void gemm_bt_kernel(const u16* __restrict__ A, const u16* __restrict__ Bt,
                    const int* __restrict__ flag,
                    int M, int N, int K, int mode,
                    u16* __restrict__ C0, u16* __restrict__ Ck, u16* __restrict__ Cv,
                    float* __restrict__ C0f)
{
    __shared__ u16 As[2][256][64];
    __shared__ u16 Bs[2][256][64];

    const int tid  = threadIdx.x;
    const int wave = tid >> 6, lane = tid & 63;
    const int l15  = lane & 15, quad = lane >> 4;
    const int wr   = wave >> 2, wc = wave & 3;

    // bijective XCD swizzle (gridDim.x % 8 == 0 for both call sites)
    const int nwg = gridDim.x;
    const int bid = blockIdx.x;
    const int swz = (bid & 7) * (nwg >> 3) + (bid >> 3);
    const int ntn = N >> 8;
    const int m0 = (swz / ntn) << 8;
    const int n0 = (swz % ntn) << 8;

    // staging: thread t loads row (t>>3) of a 64-row slab, source column
    // chunk pre-swizzled so linear LDS slot (r, p) holds chunk p ^ (r&7)
    const int trow = tid >> 3;
    const int tcol = ((tid & 7) ^ (trow & 7)) << 3;
    const u16* aS = A  + (size_t)(m0 + trow) * K + tcol;
    const u16* bS = Bt + (size_t)(n0 + trow) * K + tcol;
    const size_t slabK = (size_t)64 * K;

    u16* ASf = &As[0][0][0];
    u16* BSf = &Bs[0][0][0];
    const int dOff = tid * 8;

    // fragment read bases: A frag (i,kk) row = i*32 + wr*16 + l15,
    // physical chunk = (kk*4 + quad) ^ (row & 7)
    const int aR = (wr * 16 + l15) * 64;
    const int bR = (wc * 16 + l15) * 64;
    const int sw = l15 & 7;
    const int p0 = (quad ^ sw) * 8;
    const int p1 = ((quad + 4) ^ sw) * 8;

    f32x4 acc[8][4];
#pragma unroll
    for (int i = 0; i < 8; i++)
#pragma unroll
        for (int j = 0; j < 4; j++) acc[i][j] = (f32x4){0.f, 0.f, 0.f, 0.f};

    const int NT = K >> 6;

    // prologue: stage K-tile 0 into buf 0, drain once
#pragma unroll
    for (int q = 0; q < 4; ++q) {
        load_lds16(aS + q * slabK, ASf + q * 4096 + dOff);
        load_lds16(bS + q * slabK, BSf + q * 4096 + dOff);
    }
    WAITV(0);
    BARS();

    bf16x8 aF[4][2], bF0[2][2], bF1[2][2];

    for (int kt = 0; kt < NT - 1; ++kt) {
        const int c = kt & 1;
        const u16* Ac = ASf + c * 16384;
        const u16* Bc = BSf + c * 16384;
        u16* An = ASf + (c ^ 1) * 16384;
        u16* Bn = BSf + (c ^ 1) * 16384;
        const u16* aN = aS + (size_t)(kt + 1) * 64;
        const u16* bN = bS + (size_t)(kt + 1) * 64;

        // phase 1: frags A-h0 + B j0/1; issue A slabs 0,1 (kt+1)
        RD_A(0)
        RD_B(bF0, 0)
        load_lds16(aN,         An + dOff);
        load_lds16(aN + slabK, An + 4096 + dOff);
        WAITV(4);               // retires B-h1 of kt (needed ph2)
        BARS();
        MFMA_BLK(0, bF0, 0)

        // phase 2: frags B j2/3; issue B slabs 0,1
        RD_B(bF1, 2)
        load_lds16(bN,         Bn + dOff);
        load_lds16(bN + slabK, Bn + 4096 + dOff);
        WAITV(4);               // retires A-h1 of kt (needed ph3)
        BARS();
        MFMA_BLK(0, bF1, 2)

        // phase 3: frags A-h1; issue B slabs 2,3
        RD_A(4)
        load_lds16(bN + 2 * slabK, Bn + 8192 + dOff);
        load_lds16(bN + 3 * slabK, Bn + 12288 + dOff);
        BARS();
        MFMA_BLK(4, bF0, 0)

        // phase 4: issue A slabs 2,3
        load_lds16(aN + 2 * slabK, An + 8192 + dOff);
        load_lds16(aN + 3 * slabK, An + 12288 + dOff);
        WAITV(4);               // retires A-h0,B-h0 of kt+1 (needed next ph1)
        BARS();
        MFMA_BLK(4, bF1, 2)
    }

    // peeled last K-tile (no prefetch; drain the two remaining half-tiles)
    {
        const int c = (NT - 1) & 1;
        const u16* Ac = ASf + c * 16384;
        const u16* Bc = BSf + c * 16384;
        RD_A(0)
        RD_B(bF0, 0)
        WAITV(2);
        BARS();
        MFMA_BLK(0, bF0, 0)
        RD_B(bF1, 2)
        WAITV(0);
        BARS();
        MFMA_BLK(0, bF1, 2)
        RD_A(4)
        BARS();
        MFMA_BLK(4, bF0, 0)
        MFMA_BLK(4, bF1, 2)
    }

    const int isF32 = *flag;
    if (mode == 0) {
#pragma unroll
        for (int j4 = 0; j4 < 4; ++j4) {
            int n = n0 + j4 * 64 + wc * 16 + l15;
#pragma unroll
            for (int i = 0; i < 8; ++i) {
                int m = m0 + i * 32 + wr * 16 + quad * 4;
#pragma unroll
                for (int r = 0; r < 4; ++r) {
                    float v = acc[i][j4][r];
                    if (isF32) C0f[(size_t)(m + r) * N + n] = v;
                    else       C0[(size_t)(m + r) * N + n] = f2b(v);
                }
            }
        }
    } else {
        // fused_qkv col n -> (mp group g, third t in {q,v,k}, head, d)
        // Q,K: [b,h,s,d]; V: [b,h,d,s] (transposed for attention B-frags)
#pragma unroll
        for (int j4 = 0; j4 < 4; ++j4) {
            int n = n0 + j4 * 64 + wc * 16 + l15;
            int g = n / 3072;
            int r3 = n - g * 3072;
            int t = r3 >> 10;            // 0=q, 1=v, 2=k (reference split order)
            int r1 = r3 & 1023;
            int head = g * 4 + (r1 >> 8);
            int d = r1 & 255;
#pragma unroll
            for (int i = 0; i < 8; ++i) {
                int m = m0 + i * 32 + wr * 16 + quad * 4;
#pragma unroll
                for (int r = 0; r < 4; ++r) {
                    int mm = m + r;
                    int bb = mm >> 11, s = mm & 2047;
                    size_t idx;
                    u16* dst;
                    if (t == 1) { dst = Cv; idx = (size_t)bb * 8388608 + (size_t)head * 524288 + (size_t)d * 2048 + s; }
                    else        { dst = (t == 0) ? C0 : Ck;
                                  idx = (size_t)bb * 8388608 + (size_t)head * 524288 + (size_t)s * 256 + d; }
                    dst[idx] = f2b(acc[i][j4][r]);
                }
            }
        }
    }
}

// ---------------- RoPE (in-place on Q,K first 64 dims, interleaved pairs) --
__global__ __launch_bounds__(256)
void rope_kernel(u16* __restrict__ Q, u16* __restrict__ Kb, const int* __restrict__ pos_ids)
{
    int idx = blockIdx.x * 256 + threadIdx.x;
    int i = idx & 31;
    int s = (idx >> 5) & 2047;
    int h = (idx >> 16) & 15;
    int b = idx >> 20;
    int pos = pos_ids[b * 2048 + s];
    float freq = __expf(-(float)(2 * i) * (9.210340371976184f / 64.0f));
    float ang = (float)pos * freq;
    float sn = sinf(ang), cs = cosf(ang);
    size_t base = ((size_t)(b * 16 + h) * 2048 + s) * 256 + 2 * i;
    float q0 = b2f(Q[base]), q1 = b2f(Q[base + 1]);
    Q[base]     = f2b(q0 * cs - q1 * sn);
    Q[base + 1] = f2b(q1 * cs + q0 * sn);
    float k0 = b2f(Kb[base]), k1 = b2f(Kb[base + 1]);
    Kb[base]     = f2b(k0 * cs - k1 * sn);
    Kb[base + 1] = f2b(k1 * cs + k0 * sn);
}

// ---------------- Flash attention (causal) --------------------------------
// Block = 128 q-rows of one (b,h); wave = 32 q-rows (2 m-tiles); k-tile = 32.
// K, Vt staged via global_load_lds into XOR-swizzled LDS (conflict-free b128).
// Grid: 512 blocks, heavy-half-first so each CU's 2 resident blocks sum to
// constant work.
__global__ __launch_bounds__(256, 2)
void attn_kernel(const u16* __restrict__ Q, const u16* __restrict__ Kb,
                 const u16* __restrict__ Vt, u16* __restrict__ att)
{
    __shared__ u16 Ks[32 * 256];    // row=key (32 chunks of 16B), chunk c at p=(c&24)|((c^row)&7)
    __shared__ u16 Vts[256 * 32];   // row=d (4 chunks), chunk c at p=c^((d>>1)&3)
    __shared__ u16 Ps[4][32][40];   // per-wave P [q][k], pitch 40

    const int tid = threadIdx.x;
    const int wave = tid >> 6, lane = tid & 63;
    const int l15 = lane & 15, quad = lane >> 4;

    const int blk = blockIdx.x;
    const int bh = blk & 31;
    const int jj = blk >> 5;
    const int qt = (jj < 8) ? (15 - jj) : (jj - 8);   // heavy-first pairing
    const int b = bh >> 4, h = bh & 15;
    const int qrow = qt * 128 + wave * 32;

    const u16* qb = Q + (size_t)bh * 524288;
    const u16* kb = Kb + (size_t)bh * 524288;
    const u16* vb = Vt + (size_t)bh * 524288;   // [d][s]

    bf16x8 qf[2][8];
#pragma unroll
    for (int mi = 0; mi < 2; mi++)
#pragma unroll
        for (int ks = 0; ks < 8; ks++)
            qf[mi][ks] = *reinterpret_cast<const bf16x8*>(
                &qb[(size_t)(qrow + mi * 16 + l15) * 256 + ks * 32 + quad * 8]);

    f32x4 O[2][16];
#pragma unroll
    for (int mi = 0; mi < 2; mi++)
#pragma unroll
        for (int dt = 0; dt < 16; dt++) O[mi][dt] = (f32x4){0.f, 0.f, 0.f, 0.f};
    float m_run[2][4], l_run[2][4];
#pragma unroll
    for (int mi = 0; mi < 2; mi++)
#pragma unroll
        for (int r = 0; r < 4; r++) { m_run[mi][r] = -1e30f; l_run[mi][r] = 0.f; }
    const float scale = 1.0f / 16.0f;

    const int nkt = qt * 4 + 4;
    for (int kt = 0; kt < nkt; kt++) {
        const int k0 = kt * 32;
#pragma unroll
        for (int t = 0; t < 4; t++) {
            int pc = wave * 256 + t * 64 + lane;
            int rk = pc >> 5, pk = pc & 31;
            int ck = (pk & 24) | ((pk ^ rk) & 7);
            load_lds16(&kb[(size_t)(k0 + rk) * 256 + ck * 8], &Ks[pc * 8]);
            int dv = pc >> 2, pv2 = pc & 3;
            int cv = pv2 ^ ((dv >> 1) & 3);
            load_lds16(&vb[(size_t)dv * 2048 + k0 + cv * 8], &Vts[pc * 8]);
        }
        __syncthreads();

        if (k0 <= qrow + 31) {   // wave-uniform guard
            f32x4 sc[2][2];
#pragma unroll
            for (int mi = 0; mi < 2; mi++)
#pragma unroll
                for (int nt = 0; nt < 2; nt++) sc[mi][nt] = (f32x4){0.f, 0.f, 0.f, 0.f};
#pragma unroll
            for (int ks = 0; ks < 8; ks++)
#pragma unroll
                for (int nt = 0; nt < 2; nt++) {
                    int row = nt * 16 + l15;
                    int c = ks * 4 + quad;
                    int p = (c & 24) | ((c ^ row) & 7);
                    bf16x8 kf = *reinterpret_cast<const bf16x8*>(&Ks[row * 256 + p * 8]);
                    sc[0][nt] = __builtin_amdgcn_mfma_f32_16x16x32_bf16(qf[0][ks], kf, sc[0][nt], 0, 0, 0);
                    sc[1][nt] = __builtin_amdgcn_mfma_f32_16x16x32_bf16(qf[1][ks], kf, sc[1][nt], 0, 0, 0);
                }

#pragma unroll
            for (int mi = 0; mi < 2; mi++) {
                float pw[2][4], mloc[4], alpha[4], sum[4];
#pragma unroll
                for (int r = 0; r < 4; r++) {
                    int qg = qrow + mi * 16 + quad * 4 + r;
#pragma unroll
                    for (int nt = 0; nt < 2; nt++) {
                        int kg = k0 + nt * 16 + l15;
                        float v = sc[mi][nt][r] * scale;
                        pw[nt][r] = (kg <= qg) ? v : -1e30f;
                    }
                    mloc[r] = fmaxf(pw[0][r], pw[1][r]);
                }
#pragma unroll
                for (int off = 1; off < 16; off <<= 1)
#pragma unroll
                    for (int r = 0; r < 4; r++)
                        mloc[r] = fmaxf(mloc[r], __shfl_xor(mloc[r], off, 16));
#pragma unroll
                for (int r = 0; r < 4; r++) {
                    float mnew = fmaxf(m_run[mi][r], mloc[r]);
                    alpha[r] = __expf(m_run[mi][r] - mnew);
                    pw[0][r] = __expf(pw[0][r] - mnew);
                    pw[1][r] = __expf(pw[1][r] - mnew);
                    sum[r] = pw[0][r] + pw[1][r];
                    m_run[mi][r] = mnew;
                }
#pragma unroll
                for (int off = 1; off < 16; off <<= 1)
#pragma unroll
                    for (int r = 0; r < 4; r++)
                        sum[r] += __shfl_xor(sum[r], off, 16);
#pragma unroll
                for (int r = 0; r < 4; r++) l_run[mi][r] = l_run[mi][r] * alpha[r] + sum[r];
#pragma unroll
                for (int dt = 0; dt < 16; dt++)
#pragma unroll
                    for (int r = 0; r < 4; r++) O[mi][dt][r] *= alpha[r];
#pragma unroll
                for (int nt = 0; nt < 2; nt++)
#pragma unroll
                    for (int r = 0; r < 4; r++)
                        Ps[wave][mi * 16 + quad * 4 + r][nt * 16 + l15] = f2b(pw[nt][r]);
            }
            bf16x8 aP0 = *reinterpret_cast<const bf16x8*>(&Ps[wave][l15][quad * 8]);
            bf16x8 aP1 = *reinterpret_cast<const bf16x8*>(&Ps[wave][16 + l15][quad * 8]);
#pragma unroll
            for (int dt = 0; dt < 16; dt++) {
                int d = dt * 16 + l15;
                int pch = quad ^ ((d >> 1) & 3);
                bf16x8 vf = *reinterpret_cast<const bf16x8*>(&Vts[d * 32 + pch * 8]);
                O[0][dt] = __builtin_amdgcn_mfma_f32_16x16x32_bf16(aP0, vf, O[0][dt], 0, 0, 0);
                O[1][dt] = __builtin_amdgcn_mfma_f32_16x16x32_bf16(aP1, vf, O[1][dt], 0, 0, 0);
            }
        }
        __syncthreads();
    }

#pragma unroll
    for (int mi = 0; mi < 2; mi++) {
        float inv[4];
#pragma unroll
        for (int r = 0; r < 4; r++) inv[r] = 1.0f / l_run[mi][r];
#pragma unroll
        for (int dt = 0; dt < 16; dt++)
#pragma unroll
            for (int r = 0; r < 4; r++) {
                int s = qrow + mi * 16 + quad * 4 + r;
                att[((size_t)b * 2048 + s) * 4096 + h * 256 + dt * 16 + l15] =
                    f2b(O[mi][dt][r] * inv[r]);
            }
    }
}

extern "C" void kernel_launch(void* const* d_in, const int* in_sizes, int n_in,
                              void* d_out, int out_size, void* d_ws, size_t ws_size,
                              hipStream_t stream)
{
    const void* hidden  = d_in[0];
    const int*  pos_ids = (const int*)d_in[1];
    const void* w_qkv   = d_in[3];
    const void* w_out   = d_in[4];

    char* ws = (char*)d_ws;
    int* flag   = (int*)ws;
    u16* qbuf   = (u16*)(ws + 256);
    u16* kbuf   = (u16*)(ws + 256 + 33554432ull);
    u16* vbuf   = (u16*)(ws + 256 + 67108864ull);          // [b,h,d,s]
    u16* att    = (u16*)(ws + 256 + 100663296ull);
    u16* hbuf   = (u16*)(ws + 256 + 134217728ull);
    u16* wqkvT  = (u16*)(ws + 256 + 167772160ull);
    u16* woutT  = (u16*)(ws + 256 + 268435456ull);

    detect_kernel<<<1, 64, 0, stream>>>((const u16*)hidden, flag);
    convert_kernel<<<8192, 256, 0, stream>>>(hidden, flag, hbuf, 2097152);
    dim3 gt1(12288 / 64, 4096 / 64);
    transpose_conv_kernel<<<gt1, 256, 0, stream>>>(w_qkv, flag, 4096, 12288, wqkvT);
    dim3 gt2(4096 / 64, 4096 / 64);
    transpose_conv_kernel<<<gt2, 256, 0, stream>>>(w_out, flag, 4096, 4096, woutT);

    gemm_bt_kernel<<<768, 512, 0, stream>>>(hbuf, wqkvT, flag, 4096, 12288, 4096,
                                            1, qbuf, kbuf, vbuf, nullptr);
    rope_kernel<<<8192, 256, 0, stream>>>(qbuf, kbuf, pos_ids);
    attn_kernel<<<512, 256, 0, stream>>>(qbuf, kbuf, vbuf, att);
    gemm_bt_kernel<<<256, 512, 0, stream>>>(att, woutT, flag, 4096, 4096, 4096,
                                            0, (u16*)d_out, nullptr, nullptr, (float*)d_out);
}